// Round 13
// baseline (11956.799 us; speedup 1.0000x reference)
//
#include <hip/hip_runtime.h>
#include <hip/hip_fp16.h>
#include <math.h>

typedef unsigned int uint;

#define Bsz 64
#define Tt  1024
#define TH  512      // entities/slices < T/2, lens >= T/2 -> enc only needed for t < 512

// LDS layout (bytes): Q 0..131072 | XS 131072 | HC 132096 | HM 133120 |
// HPF 134144 (2KB f32) | HMF 136192 (2KB f32) | PART 138240 (16KB f32) = 154624 B
#define XS_H   65536   // half offsets
#define HC_H   66048
#define HM_H   66560
#define HPF_F  33536   // float offsets
#define HMF_F  34048
#define PART_F 34560
#define SMEM_B 154624

typedef _Float16 h2 __attribute__((ext_vector_type(2)));
#if defined(__has_builtin)
#if __has_builtin(__builtin_amdgcn_fdot2)
#define HAS_FDOT2 1
#endif
#endif

__device__ __forceinline__ float sigm(float x){ return 1.f/(1.f+expf(-x)); }

#define LG0  asm volatile("s_waitcnt lgkmcnt(0)":::"memory")
#define BAR  __builtin_amdgcn_s_barrier

__device__ __forceinline__ void dot2b(uint w, uint a0, uint a1, float& s0, float& s1){
  h2 wh = __builtin_bit_cast(h2, w);
#ifdef HAS_FDOT2
  s0 = __builtin_amdgcn_fdot2(wh, __builtin_bit_cast(h2,a0), s0, false);
  s1 = __builtin_amdgcn_fdot2(wh, __builtin_bit_cast(h2,a1), s1, false);
#else
  h2 x0 = __builtin_bit_cast(h2,a0), x1 = __builtin_bit_cast(h2,a1);
  s0 = fmaf((float)wh.x,(float)x0.x, fmaf((float)wh.y,(float)x0.y, s0));
  s1 = fmaf((float)wh.x,(float)x1.x, fmaf((float)wh.y,(float)x1.y, s1));
#endif
}

// Pack weights fp16. QH/RH: R9 layout (per-(dir,wave) 4 units x 256 cells; cell c = col c,
// 8 halfs = W[32w+8u+jj][c]). GH2: E col-split layout — index
// ((((dir*8+wv)*24 + chunk)*4 + q)*64 + l): chunk=d*4+p, d<3:Wih r/z/n, d>=3:Whh r/z/n;
// lane l: col=32wv+(l&31), kh=l>>5; cell = W[g*256+col][kh*128+p*32+q*8 ..+8).
__global__ void pack_k(const float* __restrict__ Q, const float* __restrict__ R,
                       const float* __restrict__ Wih_f, const float* __restrict__ Whh_f,
                       const float* __restrict__ Wih_b, const float* __restrict__ Whh_b,
                       __half* __restrict__ Wh)
{
  int ci = blockIdx.x*256 + threadIdx.x;       // 16B cell index, 131072 total
  if (ci >= 131072) return;
  float v[8];
  if (ci < 32768){
    bool isR = ci >= 16384;
    int c0 = ci & 16383;
    int c = c0 & 255;
    int rest = c0 >> 8;                        // (d*8+w)*4+u
    int u = rest & 3, dw = rest >> 2;
    int w = dw & 7, d = dw >> 3;
    const float* S = (isR ? R : Q) + d*65536;  // [k][j]
    int k0 = 32*w + 8*u;
    #pragma unroll
    for (int j=0;j<8;++j) v[j] = S[(k0+j)*256 + c];
  } else {
    int gi = ci - 32768;                       // 98304 cells
    int l = gi & 63;
    int q = (gi >> 6) & 3;
    int r2 = gi >> 8;                          // (dir*8+wv)*24 + chunk
    int chunk = r2 % 24, dw = r2 / 24;
    int wv = dw & 7, dir = dw >> 3;
    int d = chunk >> 2, p = chunk & 3;
    int g = d % 3;
    int c = l & 31, kh = l >> 5;
    int row = g*256 + 32*wv + c;
    int k0 = kh*128 + p*32 + q*8;
    const float* W = (d >= 3) ? (dir? Whh_b : Whh_f) : (dir? Wih_b : Wih_f);
    #pragma unroll
    for (int j=0;j<8;++j) v[j] = W[row*256 + k0 + j];
  }
  __half h8[8];
  #pragma unroll
  for (int j=0;j<8;++j) h8[j] = __float2half(v[j]);
  *(uint4*)(Wh + (size_t)ci*8) = *(uint4*)h8;
}

// One WG of 512 threads per (direction, batch-pair), dir grouped per XCD.
// Q pinned in LDS (read 2x/step for free); R streamed 2x + G streamed 1x
// direct global->VGPR (1024 KB/step). E is col-split: in-wave shfl reduce,
// in-lane finalize (no GRU partials, 9 barriers/step).
__global__ __launch_bounds__(512) void scan_k(
    const int* __restrict__ sents, const int* __restrict__ lens,
    const float* __restrict__ emb,
    const float* __restrict__ bih_f, const float* __restrict__ bhh_f,
    const float* __restrict__ bih_b, const float* __restrict__ bhh_b,
    const __half* __restrict__ Wh, float* __restrict__ enc)
{
  extern __shared__ float sm[];
  __half* smH = (__half*)sm;

  const int bx = blockIdx.x;                 // 0..63
  const int dir  = ((bx & 7) >= 4) ? 1 : 0;  // dir constant per XCD residue class
  const int pair = (bx >> 3)*4 + (bx & 3);   // 0..31
  const int b0 = pair*2;
  const int tid = threadIdx.x;
  const int wv = tid >> 6, ln = tid & 63;
  const int cj = tid & 255, cb = tid >> 8;   // mog finalize (col, batch)
  const int khE = ln >> 5;                   // E k-half
  const int colE = (wv << 5) + (ln & 31);    // E column

  const __half* RB  = Wh + 131072 + (size_t)((dir*8+wv)*4)*2048;
  const uint4* Gp4  = (const uint4*)(Wh + 262144) + (size_t)(dir*8+wv)*6144;
  const float* bih = dir ? bih_b : bih_f;
  const float* bhh = dir ? bhh_b : bhh_f;

  const int len0 = lens[b0], len1 = lens[b0+1];
  const float biEr = bih[colE], biEz = bih[colE+256], biEn = bih[colE+512];
  const float bhEr = bhh[colE], bhEz = bhh[colE+256], bhEn = bhh[colE+512];

  int nsteps, t, tstep;
  if (!dir){ nsteps = TH; t = 0; tstep = 1; }                        // fwd: t<512 observable
  else { int mx = max(len0,len1); nsteps = mx; t = mx-1; tstep = -1; } // bwd: h==0 while masked

  // ---- load Q into LDS (128 KB, layout == pack cells) ----
  {
    const uint4* Qg = (const uint4*)Wh + (size_t)dir*8192;
    uint4* Ql = (uint4*)sm;
    #pragma unroll
    for (int i=0;i<16;++i) Ql[tid + i*512] = Qg[tid + i*512];
  }
  smH[HC_H + tid] = (__half)0.f;             // hcs zero (512)
  sm[HPF_F + tid] = 0.f;                     // h f32 zero (512)

  auto dot4 = [&](const uint4& W, const uint4& A0, const uint4& A1, float& a0, float& a1){
    dot2b(W.x, A0.x, A1.x, a0, a1);
    dot2b(W.y, A0.y, A1.y, a0, a1);
    dot2b(W.z, A0.z, A1.z, a0, a1);
    dot2b(W.w, A0.w, A1.w, a0, a1);
  };

  // mog phase, Q from LDS (k-split, parts to PART)
  auto mog_part_lds = [&](int actsHO){
    float2 acc[4];
    acc[0]=acc[1]=acc[2]=acc[3]=make_float2(0.f,0.f);
    #pragma unroll
    for (int u=0; u<4; ++u){
      const uint4* qb = (const uint4*)((char*)sm + wv*16384 + u*4096);
      uint4 W0 = qb[ln], W1 = qb[ln+64], W2 = qb[ln+128], W3 = qb[ln+192];
      const int k8 = 4*wv + u;
      const uint4 a0 = *(const uint4*)(smH + actsHO + k8*8);
      const uint4 a1 = *(const uint4*)(smH + actsHO + 256 + k8*8);
      dot4(W0, a0, a1, acc[0].x, acc[0].y);
      dot4(W1, a0, a1, acc[1].x, acc[1].y);
      dot4(W2, a0, a1, acc[2].x, acc[2].y);
      dot4(W3, a0, a1, acc[3].x, acc[3].y);
    }
    #pragma unroll
    for (int q=0;q<4;++q)
      *(float2*)(sm + PART_F + wv*512 + (ln+64*q)*2) = acc[q];
  };

  // mog phase, R streamed (double-buffer, persistent P primed across phases)
  uint4 P0, P1, P2, P3;
  { const uint4* p = (const uint4*)RB;
    P0 = p[ln]; P1 = p[ln+64]; P2 = p[ln+128]; P3 = p[ln+192]; }
  auto mog_part_glb = [&](int actsHO){
    float2 acc[4];
    acc[0]=acc[1]=acc[2]=acc[3]=make_float2(0.f,0.f);
    uint4 Wc0=P0, Wc1=P1, Wc2=P2, Wc3=P3;
    #pragma unroll
    for (int u=0; u<4; ++u){
      uint4 Wn0,Wn1,Wn2,Wn3;
      { const uint4* p = (const uint4*)(RB + ((u+1)&3)*2048);   // u=3 -> unit0 reprime
        Wn0=p[ln]; Wn1=p[ln+64]; Wn2=p[ln+128]; Wn3=p[ln+192]; }
      const int k8 = 4*wv + u;
      const uint4 a0 = *(const uint4*)(smH + actsHO + k8*8);
      const uint4 a1 = *(const uint4*)(smH + actsHO + 256 + k8*8);
      dot4(Wc0, a0, a1, acc[0].x, acc[0].y);
      dot4(Wc1, a0, a1, acc[1].x, acc[1].y);
      dot4(Wc2, a0, a1, acc[2].x, acc[2].y);
      dot4(Wc3, a0, a1, acc[3].x, acc[3].y);
      if (u < 3){ Wc0=Wn0; Wc1=Wn1; Wc2=Wn2; Wc3=Wn3; }
      else      { P0=Wn0; P1=Wn1; P2=Wn2; P3=Wn3; }
    }
    #pragma unroll
    for (int q=0;q<4;++q)
      *(float2*)(sm + PART_F + wv*512 + (ln+64*q)*2) = acc[q];
  };
  // finalize mog (thread = (cj,cb)): sum 8 partials, gate, store fp16 (+opt f32) act.
  auto mog_fin = [&](float mult, int dstHO, bool alsoF32)->float{
    float ssum = 0.f;
    #pragma unroll
    for (int p=0;p<8;++p) ssum += sm[PART_F + p*512 + cj*2 + cb];
    float val = 2.f*sigm(ssum)*mult;
    smH[dstHO + cb*256 + cj] = (__half)val;
    if (alsoF32) sm[HMF_F + cb*256 + cj] = val;
    return val;
  };

  uint4 GA[4], GBb[4], GC[4];
  #define LDU2(DST, CH) do{ const uint4* p_ = Gp4 + (CH)*256; \
    DST[0]=p_[ln]; DST[1]=p_[ln+64]; DST[2]=p_[ln+128]; DST[3]=p_[ln+192]; }while(0)

  float x1 = 0.f, hm1 = 0.f;
  LG0; BAR();

  for (int s=0; s<nsteps; ++s, t+=tstep){
    int tok = sents[(b0+cb)*Tt + t];
    float x0 = emb[(size_t)tok*256 + cj];

    // A: x1 = 2sig(h@Q)*x0
    mog_part_lds(HC_H);             LG0; BAR();
    x1 = mog_fin(x0, XS_H, false);  LG0; BAR();
    // B: hm1 = 2sig(x1@R)*h
    mog_part_glb(XS_H);             LG0; BAR();
    { float hp = sm[HPF_F + cb*256 + cj];
      hm1 = mog_fin(hp, HM_H, false); }  LG0; BAR();
    // C: x2 = 2sig(hm1@Q)*x1
    mog_part_lds(HM_H);             LG0; BAR();
    x1 = mog_fin(x1, XS_H, false);  LG0; BAR();     // x1 now holds x2
    // D: hm2 = 2sig(x2@R)*hm1   (+prime E ring chunks 0,1)
    mog_part_glb(XS_H);
    LDU2(GA, 0); LDU2(GBb, 1);
    LG0; BAR();
    mog_fin(hm1, HM_H, true);       LG0; BAR();

    // E: GRU col-split — wave owns 32 cols; 24 chunks, 3-deep ring; shfl reduce.
    {
      float2 ag[6];
      #pragma unroll
      for (int i=0;i<6;++i) ag[i] = make_float2(0.f,0.f);

      #define E_STEP(C, CUR, NXT, DOLOAD) { \
        if (DOLOAD) LDU2(NXT, (C)+2); \
        const int d_ = (C)>>2, p_ = (C)&3; \
        const int aHO = (d_<3) ? XS_H : HM_H; \
        const int ab = aHO + khE*128 + p_*32; \
        _Pragma("unroll") \
        for (int q=0;q<4;++q){ \
          const uint4 ea0 = *(const uint4*)(smH + ab + q*8); \
          const uint4 ea1 = *(const uint4*)(smH + ab + 256 + q*8); \
          dot4(CUR[q], ea0, ea1, ag[d_].x, ag[d_].y); \
        } }

      E_STEP(0,  GA,  GC,  1); E_STEP(1,  GBb, GA,  1); E_STEP(2,  GC,  GBb, 1);
      E_STEP(3,  GA,  GC,  1); E_STEP(4,  GBb, GA,  1); E_STEP(5,  GC,  GBb, 1);
      E_STEP(6,  GA,  GC,  1); E_STEP(7,  GBb, GA,  1); E_STEP(8,  GC,  GBb, 1);
      E_STEP(9,  GA,  GC,  1); E_STEP(10, GBb, GA,  1); E_STEP(11, GC,  GBb, 1);
      E_STEP(12, GA,  GC,  1); E_STEP(13, GBb, GA,  1); E_STEP(14, GC,  GBb, 1);
      E_STEP(15, GA,  GC,  1); E_STEP(16, GBb, GA,  1); E_STEP(17, GC,  GBb, 1);
      E_STEP(18, GA,  GC,  1); E_STEP(19, GBb, GA,  1); E_STEP(20, GC,  GBb, 1);
      E_STEP(21, GA,  GC,  1); E_STEP(22, GBb, GA,  0); E_STEP(23, GC,  GBb, 0);
      #undef E_STEP

      #pragma unroll
      for (int d=0; d<6; ++d){
        ag[d].x += __shfl_xor(ag[d].x, 32);
        ag[d].y += __shfl_xor(ag[d].y, 32);
      }
      if (ln < 32){
        #pragma unroll
        for (int b=0; b<2; ++b){
          float gir = b? ag[0].y: ag[0].x, giz = b? ag[1].y: ag[1].x, gin = b? ag[2].y: ag[2].x;
          float ghr = b? ag[3].y: ag[3].x, ghz = b? ag[4].y: ag[4].x, ghn = b? ag[5].y: ag[5].x;
          float r = sigm(gir + biEr + ghr + bhEr);
          float z = sigm(giz + biEz + ghz + bhEz);
          float n = tanhf(gin + biEn + r*(ghn + bhEn));
          float hm2v  = sm[HMF_F + b*256 + colE];
          float hprev = sm[HPF_F + b*256 + colE];
          float uu = (1.f - z)*n + z*hm2v;
          bool m = (t < (b ? len1 : len0));
          float hnew = m ? uu : hprev;
          smH[HC_H + b*256 + colE] = (__half)hnew;
          sm[HPF_F + b*256 + colE] = hnew;
          if (m && t < TH)
            atomicAdd(&enc[((size_t)(b0+b)*TH + t)*256 + colE], uu);
        }
      }
    }
    LG0; BAR();
  }
  #undef LDU2
}

// One WG per batch element. Reproduces gate_attention + attention + dense exactly.
__global__ __launch_bounds__(256) void epi_k(
    const float* __restrict__ enc,
    const int* __restrict__ entities, const int* __restrict__ slices,
    const float* __restrict__ slice_lens,
    const int* __restrict__ entity_masks, const int* __restrict__ slice_masks,
    const float* __restrict__ ent_W, const float* __restrict__ ent_b,
    const float* __restrict__ att_w,
    const float* __restrict__ dense_W, const float* __restrict__ dense_b,
    float* __restrict__ out)
{
    const int b = blockIdx.x;
    const int j = threadIdx.x;
    const int wave = j >> 6, lane = j & 63;

    __shared__ float ee[8][256];
    __shared__ float p[256];
    __shared__ float rela[256];
    __shared__ float sc[264];
    __shared__ float red[4];
    __shared__ float aw[256];
    __shared__ int   spos[256];

    aw[j]   = att_w[j];
    spos[j] = slices[b * 256 + j];
    #pragma unroll
    for (int e = 0; e < 8; ++e)
        ee[e][j] = enc[((size_t)b * TH + entities[b * 8 + e]) * 256 + j];
    __syncthreads();

    float entWj = ent_W[j];
    for (int e = 0; e < 8; ++e) {
        float v = ee[e][j] * entWj;
        #pragma unroll
        for (int o = 32; o > 0; o >>= 1) v += __shfl_down(v, o);
        if (lane == 0) red[wave] = v;
        __syncthreads();
        if (j == 0) sc[e] = red[0] + red[1] + red[2] + red[3] + ent_b[0];
        __syncthreads();
    }
    float mx = -INFINITY;
    float ewv[8];
    #pragma unroll
    for (int e = 0; e < 8; ++e) {
        float v = entity_masks[b * 8 + e] ? sc[e] : -INFINITY;
        ewv[e] = v; mx = fmaxf(mx, v);
    }
    float den = 0.f;
    #pragma unroll
    for (int e = 0; e < 8; ++e) {
        ewv[e] = entity_masks[b * 8 + e] ? expf(ewv[e] - mx) : 0.f;
        den += ewv[e];
    }
    float accp = 0.f;
    #pragma unroll
    for (int e = 0; e < 8; ++e) accp += (ewv[e] / den) * ee[e][j];
    p[j] = tanhf(accp);
    __syncthreads();

    for (int s0 = wave; s0 < 256; s0 += 4) {
        const float* row = enc + ((size_t)b * TH + spos[s0]) * 256;
        float v = 0.f;
        #pragma unroll
        for (int i = 0; i < 4; ++i) { int c = lane + 64 * i; v += row[c] * p[c]; }
        #pragma unroll
        for (int o = 32; o > 0; o >>= 1) v += __shfl_down(v, o);
        if (lane == 0) sc[s0] = v;
    }
    __syncthreads();

    float sl  = slice_lens[b];
    int   smk = slice_masks[b * 256 + j];
    float wv  = smk ? sc[j] : -INFINITY;
    float bm = wv;
    #pragma unroll
    for (int o = 32; o > 0; o >>= 1) bm = fmaxf(bm, __shfl_down(bm, o));
    __syncthreads();
    if (lane == 0) red[wave] = bm;
    __syncthreads();
    bm = fmaxf(fmaxf(red[0], red[1]), fmaxf(red[2], red[3]));
    float ex = smk ? expf(wv - bm) : 0.f;
    float sm2 = ex;
    #pragma unroll
    for (int o = 32; o > 0; o >>= 1) sm2 += __shfl_down(sm2, o);
    __syncthreads();
    if (lane == 0) red[wave] = sm2;
    __syncthreads();
    sm2 = red[0] + red[1] + red[2] + red[3];
    float ww = ex / sm2 * sl;
    float rl = (ww > 0.05f) ? (ww / sl) : 0.f;   // BETA = 0.05
    float rm = rl;
    #pragma unroll
    for (int o = 32; o > 0; o >>= 1) rm = fmaxf(rm, __shfl_down(rm, o));
    __syncthreads();
    if (lane == 0) red[wave] = rm;
    __syncthreads();
    rm = fmaxf(fmaxf(red[0], red[1]), fmaxf(red[2], red[3]));
    rl = rl / rm;
    rela[j] = rl;
    __syncthreads();

    for (int n = wave; n < 264; n += 4) {
        float v = 0.f;
        if (n < 8) {
            #pragma unroll
            for (int i = 0; i < 4; ++i) { int c = lane + 64 * i; v += tanhf(ee[n][c]) * aw[c]; }
        } else {
            int s0 = n - 8;
            const float* row = enc + ((size_t)b * TH + spos[s0]) * 256;
            float rl2 = rela[s0];
            #pragma unroll
            for (int i = 0; i < 4; ++i) { int c = lane + 64 * i; v += tanhf(rl2 * row[c]) * aw[c]; }
        }
        #pragma unroll
        for (int o = 32; o > 0; o >>= 1) v += __shfl_down(v, o);
        if (lane == 0) sc[n] = v;
    }
    __syncthreads();

    float a1 = sc[j];       a1 = (a1 == 0.f) ? -INFINITY : a1;
    float a2 = (j < 8) ? sc[256 + j] : -INFINITY;
    if (a2 == 0.f) a2 = -INFINITY;
    float am = fmaxf(a1, a2);
    #pragma unroll
    for (int o = 32; o > 0; o >>= 1) am = fmaxf(am, __shfl_down(am, o));
    __syncthreads();
    if (lane == 0) red[wave] = am;
    __syncthreads();
    am = fmaxf(fmaxf(red[0], red[1]), fmaxf(red[2], red[3]));
    float e1 = (a1 == -INFINITY) ? 0.f : expf(a1 - am);
    float e2 = (a2 == -INFINITY) ? 0.f : expf(a2 - am);
    float esum = e1 + e2;
    #pragma unroll
    for (int o = 32; o > 0; o >>= 1) esum += __shfl_down(esum, o);
    __syncthreads();
    if (lane == 0) red[wave] = esum;
    __syncthreads();
    esum = red[0] + red[1] + red[2] + red[3];
    __syncthreads();
    sc[j] = e1 / esum;
    if (j < 8) sc[256 + j] = e2 / esum;
    __syncthreads();

    float att = 0.f;
    #pragma unroll
    for (int n = 0; n < 8; ++n) att += sc[n] * ee[n][j];
    for (int s0 = 0; s0 < 256; ++s0) {
        float scn = sc[8 + s0];
        if (scn > 0.f)
            att += scn * rela[s0] * enc[((size_t)b * TH + spos[s0]) * 256 + j];
    }
    float ta = tanhf(att);

    for (int l = 0; l < 19; ++l) {
        float v = ta * dense_W[l * 256 + j];
        #pragma unroll
        for (int o = 32; o > 0; o >>= 1) v += __shfl_down(v, o);
        __syncthreads();
        if (lane == 0) red[wave] = v;
        __syncthreads();
        if (j == 0) out[b * 19 + l] = red[0] + red[1] + red[2] + red[3] + dense_b[l];
    }
}

extern "C" void kernel_launch(void* const* d_in, const int* in_sizes, int n_in,
                              void* d_out, int out_size, void* d_ws, size_t ws_size,
                              hipStream_t stream) {
    (void)in_sizes; (void)n_in; (void)out_size; (void)ws_size;
    const int*   sents        = (const int*)d_in[0];
    const int*   lens         = (const int*)d_in[1];
    const int*   entities     = (const int*)d_in[2];
    const int*   slices       = (const int*)d_in[3];
    const float* slice_lens   = (const float*)d_in[4];
    const int*   entity_masks = (const int*)d_in[5];
    const int*   slice_masks  = (const int*)d_in[6];
    const float* emb          = (const float*)d_in[7];
    const float* Q            = (const float*)d_in[8];
    const float* R            = (const float*)d_in[9];
    const float* Wih_f        = (const float*)d_in[10];
    const float* Whh_f        = (const float*)d_in[11];
    const float* bih_f        = (const float*)d_in[12];
    const float* bhh_f        = (const float*)d_in[13];
    const float* Wih_b        = (const float*)d_in[14];
    const float* Whh_b        = (const float*)d_in[15];
    const float* bih_b        = (const float*)d_in[16];
    const float* bhh_b        = (const float*)d_in[17];
    const float* ent_W        = (const float*)d_in[18];
    const float* ent_b        = (const float*)d_in[19];
    const float* att_w        = (const float*)d_in[20];
    const float* dense_W      = (const float*)d_in[21];
    const float* dense_b      = (const float*)d_in[22];

    // ws: enc [64][512][256] f32 (33.5MB) | Wh 1048576 halfs (2MB)
    float*  enc = (float*)d_ws;
    __half* Wh  = (__half*)(enc + (size_t)Bsz * TH * 256);

    hipFuncSetAttribute(reinterpret_cast<const void*>(scan_k),
                        hipFuncAttributeMaxDynamicSharedMemorySize, SMEM_B);

    hipMemsetAsync(enc, 0, (size_t)Bsz * TH * 256 * sizeof(float), stream);
    pack_k<<<512, 256, 0, stream>>>(Q, R, Wih_f, Whh_f, Wih_b, Whh_b, Wh);
    scan_k<<<64, 512, SMEM_B, stream>>>(sents, lens, emb,
                                        bih_f, bhh_f, bih_b, bhh_b,
                                        Wh, enc);
    epi_k<<<64, 256, 0, stream>>>(enc, entities, slices, slice_lens,
                                  entity_masks, slice_masks, ent_W, ent_b,
                                  att_w, dense_W, dense_b, (float*)d_out);
}